// Round 2
// 464.382 us; speedup vs baseline: 1.0518x; 1.0518x over previous
//
#include <hip/hip_runtime.h>
#include <hip/hip_bf16.h>
#include <stdint.h>

#define SLOPE  0.2f
#define PN     64       // nodes per proj block

typedef float f32x4 __attribute__((ext_vector_type(4)));   // clang-native vec4 (NT-store-compatible)

union FU { float f; unsigned int u; };
__device__ __forceinline__ float ubits(unsigned int u) { FU c; c.u = u; return c.f; }
__device__ __forceinline__ unsigned short f2bf(float f) {
    FU c; c.f = f;
    unsigned int lsb = (c.u >> 16) & 1u;
    c.u += 0x7fffu + lsb;                 // round-to-nearest-even
    return (unsigned short)(c.u >> 16);
}

// ---------------- K0: prep + zero ----------------
// blocks 0..63:  Wt[k][c'] = bf16(W[o][k]) h-major channel c' (o = (c'&63)*4 + (c'>>6))
// block 64:      Wl[8][64], bl[8], biasP[c']
// blocks 65..:   zero deg/cnt
__global__ __launch_bounds__(256) void prep_kernel(
    const float* __restrict__ W, const float* __restrict__ bias,
    const float* __restrict__ a_l, const float* __restrict__ a_r,
    unsigned short* __restrict__ Wt, float* __restrict__ biasP,
    float* __restrict__ Wl, float* __restrict__ bl,
    int* __restrict__ deg, int* __restrict__ cnt, int N)
{
    int t = threadIdx.x;
    if (blockIdx.x < 64) {
        int g = blockIdx.x * 256 + t;       // 16384 elements
        int k = g >> 8, cp = g & 255;
        int o = (cp & 63) * 4 + (cp >> 6);
        Wt[k * 256 + cp] = f2bf(W[o * 64 + k]);
    } else if (blockIdx.x == 64) {
        for (int id = t; id < 512; id += 256) {
            int x = id >> 6, k = id & 63;
            int h = x & 3;
            const float* v = (x < 4) ? a_l : a_r;
            float s = 0.f;
            for (int d = 0; d < 64; d++) {
                int o = d * 4 + h;
                s += v[o] * W[o * 64 + k];
            }
            Wl[id] = s;
        }
        if (t < 8) {
            int h = t & 3;
            const float* v = (t < 4) ? a_l : a_r;
            float s = 0.f;
            for (int d = 0; d < 64; d++) { int o = d * 4 + h; s += v[o] * bias[o]; }
            bl[t] = s;
        }
        {
            int cp = t;
            int o = (cp & 63) * 4 + (cp >> 6);
            biasP[cp] = bias[o];
        }
    } else {
        int i = (blockIdx.x - 65) * 256 + t;
        if (i < N) { deg[i] = 0; cnt[i] = 0; }
    }
}

// ---------------- K2: proj — Zb(h-major bf16) = feat @ W^T + bias, fused el/er ----------------
__global__ __launch_bounds__(256) void proj_kernel(
    const float4* __restrict__ feat4,
    const uint4* __restrict__ Wt4,      // [64][32] uint4 (8 bf16 each), h-major channels
    const float* __restrict__ biasP,
    const float* __restrict__ Wl, const float* __restrict__ bl,
    unsigned short* __restrict__ Zb,
    float* __restrict__ el, float* __restrict__ er, int N)
{
    __shared__ float          fT[64][68];        // [k][node] fp32
    __shared__ unsigned short wT[64][264];       // [k][c'] bf16
    __shared__ float          WlS[8][68];
    __shared__ float          blS[8];

    int t = threadIdx.x;
    int nodeBase = blockIdx.x * PN;

    for (int p = t; p < 64 * 32; p += 256) {
        int k = p >> 5, cu = p & 31;
        *(uint4*)&wT[k][cu * 8] = Wt4[p];
    }
    for (int p = t; p < PN * 16; p += 256) {
        int n = p >> 4, kq = p & 15;
        int gn = nodeBase + n;
        float4 v = make_float4(0.f, 0.f, 0.f, 0.f);
        if (gn < N) v = feat4[(size_t)gn * 16 + kq];
        fT[kq * 4 + 0][n] = v.x; fT[kq * 4 + 1][n] = v.y;
        fT[kq * 4 + 2][n] = v.z; fT[kq * 4 + 3][n] = v.w;
    }
    for (int p = t; p < 512; p += 256) WlS[p >> 6][p & 63] = Wl[p];
    if (t < 8) blS[t] = bl[t];
    __syncthreads();

    int cg = t & 31;     // channel group: c' = cg*8 .. cg*8+7
    int ng = t >> 5;     // node group:    n  = ng*8 .. ng*8+7

    float bj[8];
    {
        float4 b0 = *(const float4*)&biasP[cg * 8];
        float4 b1 = *(const float4*)&biasP[cg * 8 + 4];
        bj[0] = b0.x; bj[1] = b0.y; bj[2] = b0.z; bj[3] = b0.w;
        bj[4] = b1.x; bj[5] = b1.y; bj[6] = b1.z; bj[7] = b1.w;
    }
    float acc[8][8];
    #pragma unroll
    for (int u = 0; u < 8; u++)
        #pragma unroll
        for (int j = 0; j < 8; j++) acc[u][j] = bj[j];

    for (int k = 0; k < 64; k++) {
        float4 fa = *(const float4*)&fT[k][ng * 8];
        float4 fb = *(const float4*)&fT[k][ng * 8 + 4];
        uint4  wv = *(const uint4*)&wT[k][cg * 8];
        float f[8] = { fa.x, fa.y, fa.z, fa.w, fb.x, fb.y, fb.z, fb.w };
        float w[8];
        w[0] = ubits(wv.x << 16); w[1] = ubits(wv.x & 0xffff0000u);
        w[2] = ubits(wv.y << 16); w[3] = ubits(wv.y & 0xffff0000u);
        w[4] = ubits(wv.z << 16); w[5] = ubits(wv.z & 0xffff0000u);
        w[6] = ubits(wv.w << 16); w[7] = ubits(wv.w & 0xffff0000u);
        #pragma unroll
        for (int u = 0; u < 8; u++)
            #pragma unroll
            for (int j = 0; j < 8; j++)
                acc[u][j] += f[u] * w[j];
    }

    #pragma unroll
    for (int u = 0; u < 8; u++) {
        int gn = nodeBase + ng * 8 + u;
        if (gn < N) {
            unsigned int pk[4];
            #pragma unroll
            for (int j = 0; j < 4; j++)
                pk[j] = (unsigned int)f2bf(acc[u][2 * j]) |
                        ((unsigned int)f2bf(acc[u][2 * j + 1]) << 16);
            uint4 sv = make_uint4(pk[0], pk[1], pk[2], pk[3]);
            *(uint4*)(Zb + (size_t)gn * 256 + cg * 8) = sv;
        }
    }

    // epilogue: el/er (fp32, from fp32 fT)
    for (int r = 0; r < 2; r++) {
        int id = t + 256 * r;
        int n = id >> 3, x = id & 7;
        int gn = nodeBase + n;
        if (gn < N) {
            float e = blS[x];
            #pragma unroll 8
            for (int k = 0; k < 64; k++) e += fT[k][n] * WlS[x][k];
            if (x < 4) el[(size_t)gn * 4 + x] = e;
            else       er[(size_t)gn * 4 + (x - 4)] = e;
        }
    }
}

// ---------------- K3: degree histogram ----------------
__global__ __launch_bounds__(256) void hist_kernel(const int* __restrict__ row, int* __restrict__ deg, int E) {
    int e = blockIdx.x * 256 + threadIdx.x;
    if (e < E) atomicAdd(&deg[row[e]], 1);
}

// ---------------- K4: per-chunk sums (chunk = 1024) ----------------
__global__ __launch_bounds__(256) void scan_sums(const int* __restrict__ deg, int* __restrict__ bsums, int N) {
    __shared__ int lds[256];
    int t = threadIdx.x;
    int base = blockIdx.x * 1024;
    int v = 0;
    for (int q = 0; q < 4; q++) { int g = base + t * 4 + q; if (g < N) v += deg[g]; }
    lds[t] = v; __syncthreads();
    for (int off = 128; off >= 1; off >>= 1) {
        if (t < off) lds[t] += lds[t + off];
        __syncthreads();
    }
    if (t == 0) bsums[blockIdx.x] = lds[0];
}

// ---------------- K5: parallel exclusive scan of chunk sums (nb <= 256) ----------------
__global__ __launch_bounds__(256) void scan_top(int* __restrict__ bsums, int nb) {
    __shared__ int s[256];
    int t = threadIdx.x;
    s[t] = (t < nb) ? bsums[t] : 0;
    __syncthreads();
    for (int off = 1; off < 256; off <<= 1) {
        int v = (t >= off) ? s[t - off] : 0;
        __syncthreads();
        s[t] += v;
        __syncthreads();
    }
    if (t < nb) bsums[t] = (t > 0) ? s[t - 1] : 0;
}

// ---------------- K6: per-chunk exclusive scan -> offsets ----------------
__global__ __launch_bounds__(256) void scan_chunks(
    const int* __restrict__ deg, const int* __restrict__ bsums,
    int* __restrict__ offs, int N)
{
    __shared__ int lds[256];
    int t = threadIdx.x;
    int base = blockIdx.x * 1024;
    int vals[4]; int s = 0;
    for (int q = 0; q < 4; q++) { int g = base + t * 4 + q; vals[q] = (g < N) ? deg[g] : 0; s += vals[q]; }
    lds[t] = s; __syncthreads();
    for (int off = 1; off < 256; off <<= 1) {
        int add = (t >= off) ? lds[t - off] : 0;
        __syncthreads();
        lds[t] += add;
        __syncthreads();
    }
    int prefix = bsums[blockIdx.x] + (t > 0 ? lds[t - 1] : 0);
    for (int q = 0; q < 4; q++) {
        int g = base + t * 4 + q;
        if (g < N) { offs[g] = prefix; prefix += vals[q]; }
    }
}

// ---------------- K7: scatter edges into CSR by destination ----------------
__global__ __launch_bounds__(256) void scatter_kernel(
    const int* __restrict__ row, const int* __restrict__ col,
    const int* __restrict__ offs, int* __restrict__ cnt,
    int* __restrict__ csr, int E)
{
    int e = blockIdx.x * 256 + threadIdx.x;
    if (e < E) {
        int r = row[e];
        int pos = offs[r] + atomicAdd(&cnt[r], 1);
        csr[pos] = col[e];
    }
}

// ---------------- K8: wave-per-destination flash softmax + aggregation ----------------
// Zb is h-major (c' = h*64+d). Lane owns c' = 4*lane .. 4*lane+3  (head hsel = lane>>4).
// Score side: lane = 4*e_local + hh (hh = lane&3).
//
// Pipelined trip structure:
//   - csr values for trip t are PREFETCHED during trip t-1 -> `c` is in registers
//     at trip start.
//   - er gather + cq broadcasts + Zb gathers issue FIRST (Zb addresses depend only
//     on csr, NOT on the softmax), then next-trip csr prefetch.
//   - softmax reduce/rescale VALU+DS work runs while the Zb gathers are in flight.
//   Previously the cq broadcasts sat behind the softmax shuffles in the per-wave DS
//   FIFO, so the er-gather and Zb-gather latencies serialized (~2x the needed chain).
// Second half of each 16-slot trip is predicated on wave-uniform cnt>8 (scalar
// branch) to skip junk node-0 gathers + FMAs on tail trips.
__global__ __launch_bounds__(256) void gat_aggregate(
    const unsigned short* __restrict__ Zb, const float* __restrict__ el,
    const float* __restrict__ er, const int* __restrict__ offs,
    const int* __restrict__ deg, const int* __restrict__ csr,
    float* __restrict__ out, int N)
{
    __shared__ float ob[4][256];          // per-wave output transpose staging
    int lane = threadIdx.x & 63;
    int w = threadIdx.x >> 6;
    int i = blockIdx.x * 4 + w;
    if (i >= N) return;

    int start = offs[i], dg = deg[i];
    int eL = lane >> 2, hh = lane & 3;
    float elh = el[(size_t)i * 4 + hh];

    float m = -3.0e38f;       // running max for head hh (score side)
    float m_h = -3.0e38f;     // running max for head hsel (accumulator side)
    float l = 0.f;
    float a0 = 0.f, a1 = 0.f, a2 = 0.f, a3 = 0.f;
    int hsel = lane >> 4;     // head of this lane's output channels

    // preload trip-0 edge ids (inactive slots -> node 0: its row stays L1-hot)
    int c = 0;
    if (eL < dg) c = csr[start + eL];

    for (int base = 0; base < dg; base += 16) {
        int cnt = min(16, dg - base);
        bool half2 = (cnt > 8);           // wave-uniform

        // (1) er gather for the score — depends only on c, issue first
        float ev = er[(size_t)c * 4 + hh];

        // (2) broadcast edge ids and issue ALL Zb gathers before any softmax work
        int   cq[16];
        uint2 zw[16];
        #pragma unroll
        for (int q = 0; q < 8; q++) cq[q] = __shfl(c, q * 4);
        #pragma unroll
        for (int q = 0; q < 8; q++)
            zw[q] = ((const uint2*)(Zb + ((size_t)cq[q] << 8)))[lane];
        if (half2) {
            #pragma unroll
            for (int q = 8; q < 16; q++) cq[q] = __shfl(c, q * 4);
            #pragma unroll
            for (int q = 8; q < 16; q++)
                zw[q] = ((const uint2*)(Zb + ((size_t)cq[q] << 8)))[lane];
        }

        // (3) prefetch next trip's edge ids (arrives during consume phase)
        int rem = dg - base - 16;
        int cn = 0;
        if (rem > 0 && eL < rem) cn = csr[start + base + 16 + eL];

        // (4) softmax — overlaps with Zb gather flight time
        float e  = elh + ev;
        float sc = (eL < cnt) ? (e > 0.f ? e : SLOPE * e) : -3.0e38f;
        float v = sc;
        v = fmaxf(v, __shfl_xor(v, 4));
        v = fmaxf(v, __shfl_xor(v, 8));
        v = fmaxf(v, __shfl_xor(v, 16));
        v = fmaxf(v, __shfl_xor(v, 32));
        float mnew = fmaxf(m, v);                 // head hh's new max
        float a = __expf(sc - mnew);              // inactive: exp(-3e38)=0
        float sv = a;
        sv += __shfl_xor(sv, 4);
        sv += __shfl_xor(sv, 8);
        sv += __shfl_xor(sv, 16);
        sv += __shfl_xor(sv, 32);
        l = l * __expf(m - mnew) + sv;
        m = mnew;

        // accumulator rescale in head hsel's frame
        float mn_h = __shfl(mnew, hsel);          // lane hsel has hh==hsel
        float r = __expf(m_h - mn_h);             // first chunk: exp(-huge)=0
        a0 *= r; a1 *= r; a2 *= r; a3 *= r;
        m_h = mn_h;

        // (5) consume gathers
        #pragma unroll
        for (int q = 0; q < 8; q++) {
            float al = __shfl(a, q * 4 + hsel);
            a0 += al * ubits(zw[q].x << 16);
            a1 += al * ubits(zw[q].x & 0xffff0000u);
            a2 += al * ubits(zw[q].y << 16);
            a3 += al * ubits(zw[q].y & 0xffff0000u);
        }
        if (half2) {
            #pragma unroll
            for (int q = 8; q < 16; q++) {
                float al = __shfl(a, q * 4 + hsel);
                a0 += al * ubits(zw[q].x << 16);
                a1 += al * ubits(zw[q].x & 0xffff0000u);
                a2 += al * ubits(zw[q].y << 16);
                a3 += al * ubits(zw[q].y & 0xffff0000u);
            }
        }
        c = cn;
    }

    float lh  = __shfl(l, hsel);                  // head hsel's expsum (rel. m_hsel)
    float inv = (lh > 0.f) ? 1.0f / lh : 0.f;
    // transpose through wave-local LDS so the global write is one coalesced
    // nontemporal float4 per lane (full 64B lines; avoids NT write-through RMW
    // overhead of the old 4B-scatter pattern: WRITE_SIZE 155MB -> ~105MB)
    int dbase = 4 * (lane & 15);
    ob[w][(dbase + 0) * 4 + hsel] = a0 * inv;
    ob[w][(dbase + 1) * 4 + hsel] = a1 * inv;
    ob[w][(dbase + 2) * 4 + hsel] = a2 * inv;
    ob[w][(dbase + 3) * 4 + hsel] = a3 * inv;
    // same-wave DS ops complete in order; compiler inserts the lgkmcnt wait
    f32x4 o = *(const f32x4*)&ob[w][4 * lane];    // clang-native vec type: NT-store OK
    __builtin_nontemporal_store(o, (f32x4*)(out + (size_t)i * 256) + lane);
}

// ---------------- launch ----------------
extern "C" void kernel_launch(void* const* d_in, const int* in_sizes, int n_in,
                              void* d_out, int out_size, void* d_ws, size_t ws_size,
                              hipStream_t stream)
{
    const float* feat  = (const float*)d_in[0];
    const float* W     = (const float*)d_in[1];
    const float* bias  = (const float*)d_in[2];
    const float* a_l   = (const float*)d_in[3];
    const float* a_r   = (const float*)d_in[4];
    const int*   row   = (const int*)d_in[5];
    const int*   col   = (const int*)d_in[6];
    float* out = (float*)d_out;

    int N = in_sizes[0] / 64;
    int E = in_sizes[5];

    char* ws = (char*)d_ws;
    size_t off = 0;
    auto alloc = [&](size_t bytes) -> void* {
        void* p = (void*)(ws + off);
        off += (bytes + 255) & ~(size_t)255;
        return p;
    };
    unsigned short* Zb    = (unsigned short*)alloc((size_t)N * 256 * sizeof(unsigned short));
    unsigned short* Wt    = (unsigned short*)alloc(64 * 256 * sizeof(unsigned short));
    float*          biasP = (float*)alloc(256 * sizeof(float));
    float* el    = (float*)alloc((size_t)N * 4 * sizeof(float));
    float* er    = (float*)alloc((size_t)N * 4 * sizeof(float));
    float* Wl    = (float*)alloc(512 * sizeof(float));
    float* bl    = (float*)alloc(8 * sizeof(float));
    int*   deg   = (int*)alloc((size_t)N * sizeof(int));
    int*   cnt   = (int*)alloc((size_t)N * sizeof(int));
    int*   offs  = (int*)alloc((size_t)N * sizeof(int));
    int*   bsums = (int*)alloc(4096);
    int*   csr   = (int*)alloc((size_t)E * sizeof(int));
    (void)ws_size; (void)n_in; (void)out_size;

    int NB = (N + 1023) / 1024;
    int ZB = (N + 255) / 256;

    prep_kernel<<<65 + ZB, 256, 0, stream>>>(W, bias, a_l, a_r, Wt, biasP, Wl, bl, deg, cnt, N);
    proj_kernel<<<(N + PN - 1) / PN, 256, 0, stream>>>(
        (const float4*)feat, (const uint4*)Wt, biasP, Wl, bl, Zb, el, er, N);
    hist_kernel<<<(E + 255) / 256, 256, 0, stream>>>(row, deg, E);
    scan_sums<<<NB, 256, 0, stream>>>(deg, bsums, N);
    scan_top<<<1, 256, 0, stream>>>(bsums, NB);
    scan_chunks<<<NB, 256, 0, stream>>>(deg, bsums, offs, N);
    scatter_kernel<<<(E + 255) / 256, 256, 0, stream>>>(row, col, offs, cnt, csr, E);
    gat_aggregate<<<(N + 3) / 4, 256, 0, stream>>>(Zb, el, er, offs, deg, csr, out, N);
}